// Round 12
// baseline (310.665 us; speedup 1.0000x reference)
//
#include <hip/hip_runtime.h>
#include <hip/hip_fp16.h>
#include <math.h>

#define N_NODES 50000
#define N_EDGES 800000
#define BATCH   4
#define C1      64
#define C2      32
#define BN      (BATCH * N_NODES)
#define ELL_CAP 64
#define NHALF   (N_NODES / 2)
#define NBLK_N  ((N_NODES + 255) / 256)
#define NBLK_Q  ((N_NODES + 63) / 64)    // 4 lanes/node
#define NBLK_H8 ((NHALF + 31) / 32)      // 8 lanes/unit, half the nodes
#define NBLK_N8 ((N_NODES + 31) / 32)    // 8 lanes/node

typedef unsigned short u16;

// ---------------- build ----------------

// zero per-node (line-padded) edge counters + 128-bin degree histogram
__global__ void k_zero(int* __restrict__ cnt16, int* __restrict__ hist) {
    int n = blockIdx.x * 256 + threadIdx.x;
    if (n < N_NODES) cnt16[n * 16] = 0;
    if (blockIdx.x == 0 && threadIdx.x < 128) hist[threadIdx.x] = 0;
}

// bucketed single-pass ELL fill: block bid handles edges with (dst&7)==(bid&7).
// cnt16 padded to one line/node; ell rows 128B (u16) -> single-writer-XCD lines.
__global__ void k_fill(const int* __restrict__ ei, int* __restrict__ cnt16,
                       u16* __restrict__ ell) {
    int bid = blockIdx.x;
    int r = bid & 7;
    int e = (bid >> 3) * 256 + threadIdx.x;
    if (e >= N_EDGES) return;
    int d = ei[N_EDGES + e];
    if ((d & 7) != r) return;
    int s = ei[e];
    int pos = atomicAdd(&cnt16[d * 16], 1);
    if (pos < ELL_CAP) ell[d * ELL_CAP + pos] = (u16)s;
}

// per node: compact degree, xd4 = x * dinv (batch-transposed), degree histogram
__global__ void k_prep(const int* __restrict__ cnt16, const float* __restrict__ x,
                       int* __restrict__ degc, float4* __restrict__ xd4,
                       int* __restrict__ hist) {
    int n = blockIdx.x * 256 + threadIdx.x;
    if (n >= N_NODES) return;
    int deg = cnt16[n * 16];
    degc[n] = deg;
    float di = rsqrtf((float)(deg + 1));   // +1 self-loop
    float4 w;
    w.x = x[n] * di;
    w.y = x[N_NODES + n] * di;
    w.z = x[2 * N_NODES + n] * di;
    w.w = x[3 * N_NODES + n] * di;
    xd4[n] = w;
    int bin = ((n >= NHALF) ? 64 : 0) + min(deg, 63);
    atomicAdd(&hist[bin], 1);
}

// exclusive scan of the 128-bin histogram (two independent 64-bin segments)
__global__ __launch_bounds__(128) void k_base(const int* __restrict__ hist,
                                              int* __restrict__ cursor) {
    __shared__ int buf[128];
    int t = threadIdx.x;
    int v = hist[t];
    buf[t] = v;
    __syncthreads();
    int xsum = v;
    for (int s = 1; s < 64; s <<= 1) {
        int y = ((t & 63) >= s) ? buf[t - s] : 0;
        __syncthreads();
        xsum += y;
        buf[t] = xsum;
        __syncthreads();
    }
    cursor[t] = ((t >= 64) ? NHALF : 0) + (xsum - v);
}

// counting-sort scatter: perm32[slot] = node | (deg<<16), degree-sorted per half
__global__ void k_scatter(const int* __restrict__ degc, int* __restrict__ cursor,
                          int* __restrict__ perm32) {
    int n = blockIdx.x * 256 + threadIdx.x;
    if (n >= N_NODES) return;
    int deg = degc[n];
    int bin = ((n >= NHALF) ? 64 : 0) + min(deg, 63);
    int pos = atomicAdd(&cursor[bin], 1);
    perm32[pos] = n | (min(deg, 65535) << 16);
}

// ---------------- compute ----------------

// fused: layer-1 aggregation (4 lanes/node, batch-shared float4 gathers, degree-
// sorted waves) + dense matvec per lane (lane q = batch q): y2 = dinv*(relu(px*W1+b1)@W2)
__global__ __launch_bounds__(256) void k_agg1mv(
        const float4* __restrict__ xd4, const int* __restrict__ perm32,
        const u16* __restrict__ ell,
        const float* __restrict__ W1, const float* __restrict__ b1,
        const float* __restrict__ W2, __half* __restrict__ y2h) {
    __shared__ float sW1[C1], sb1[C1], sW2[C1 * C2];
    int lt = threadIdx.x;
    for (int i = lt; i < C1; i += 256) { sW1[i] = W1[i]; sb1[i] = b1[i]; }
    for (int i = lt; i < C1 * C2; i += 256) sW2[i] = W2[i];
    __syncthreads();

    int slot = blockIdx.x * 64 + (lt >> 2);
    if (slot >= N_NODES) return;
    int pd = perm32[slot];
    int node = pd & 0xFFFF;
    int deg = pd >> 16;
    int q = lt & 3;

    const u16* rowp = ell + node * ELL_CAP;
    int last = min(deg, ELL_CAP) - 1;
    float4 a = make_float4(0.f, 0.f, 0.f, 0.f);
    if (q == 0) a = xd4[node];        // self
    for (int k = q; k <= last; k += 16) {
        int e1 = min(k + 4, last), e2 = min(k + 8, last), e3 = min(k + 12, last);
        int i0 = rowp[k], i1 = rowp[e1], i2 = rowp[e2], i3 = rowp[e3];
        float4 g0 = xd4[i0], g1 = xd4[i1], g2 = xd4[i2], g3 = xd4[i3];
        float m1 = (k + 4 <= last) ? 1.f : 0.f;
        float m2 = (k + 8 <= last) ? 1.f : 0.f;
        float m3 = (k + 12 <= last) ? 1.f : 0.f;
        a.x += (g0.x + m1 * g1.x) + (m2 * g2.x + m3 * g3.x);
        a.y += (g0.y + m1 * g1.y) + (m2 * g2.y + m3 * g3.y);
        a.z += (g0.z + m1 * g1.z) + (m2 * g2.z + m3 * g3.z);
        a.w += (g0.w + m1 * g1.w) + (m2 * g2.w + m3 * g3.w);
    }
#pragma unroll
    for (int m = 1; m <= 2; m <<= 1) {
        a.x += __shfl_xor(a.x, m, 64);
        a.y += __shfl_xor(a.y, m, 64);
        a.z += __shfl_xor(a.z, m, 64);
        a.w += __shfl_xor(a.w, m, 64);
    }

    float di = rsqrtf((float)(deg + 1));
    float px = (q == 0) ? a.x : (q == 1) ? a.y : (q == 2) ? a.z : a.w;
    px *= di;                          // lane q <- propagated input for batch q

    float acc[C2];
#pragma unroll
    for (int j = 0; j < C2; j++) acc[j] = 0.0f;
    for (int c = 0; c < C1; c++) {
        float h = fmaxf(px * sW1[c] + sb1[c], 0.0f);
        const float4* rw = (const float4*)&sW2[c * C2];
#pragma unroll
        for (int j4 = 0; j4 < C2 / 4; j4++) {
            float4 w = rw[j4];
            acc[4 * j4 + 0] += h * w.x;
            acc[4 * j4 + 1] += h * w.y;
            acc[4 * j4 + 2] += h * w.z;
            acc[4 * j4 + 3] += h * w.w;
        }
    }

    __half2 hbuf[16];
#pragma unroll
    for (int j = 0; j < 16; j++)
        hbuf[j] = __floats2half2_rn(acc[2 * j] * di, acc[2 * j + 1] * di);
    float4* dst = (float4*)(y2h + ((size_t)q * N_NODES + node) * 32);  // one 64B line, single writer
    const float4* srcb = (const float4*)hbuf;
#pragma unroll
    for (int j4 = 0; j4 < 4; j4++) dst[j4] = srcb[j4];
}

// add 8 fp16 channels (one 16B chunk) into fp32 accumulator with mask
__device__ __forceinline__ void acc8(float* a, float4 raw, float m) {
    const __half2* hp = (const __half2*)&raw;
#pragma unroll
    for (int j = 0; j < 4; j++) {
        float2 f = __half22float2(hp[j]);
        a[2 * j + 0] += m * f.x;
        a[2 * j + 1] += m * f.y;
    }
}

// layer-2 aggregation (fp16 64B rows, 1 line/edge/batch) + epilogue + layer-3 dot.
// XCD-affine: xcd=blk&7 -> batch=xcd>>1, nodehalf=xcd&1; degree-sorted units.
// 8 lanes/unit: o=edge parity, q=channel chunk. y3t store is nt (scattered 4B,
// 4 writer-XCDs per line -> bypass L2 to avoid ping-pong).
__global__ __launch_bounds__(256) void k_agg2(
        const __half* __restrict__ y2h, const int* __restrict__ perm32,
        const u16* __restrict__ ell, const float* __restrict__ b2,
        const float* __restrict__ W3, float* __restrict__ y3t) {
    int blk = blockIdx.x;
    int xcd = blk & 7;
    int batch = xcd >> 1;
    int nh = xcd & 1;
    int sub = blk >> 3;
    int lt = threadIdx.x;
    int unit = sub * 32 + (lt >> 3);
    if (unit >= NHALF) return;
    int pd = perm32[nh * NHALF + unit];
    int node = pd & 0xFFFF;
    int deg = pd >> 16;
    int o = (lt >> 2) & 1;
    int q = lt & 3;

    const float4* Yb = (const float4*)(y2h + (size_t)batch * N_NODES * 32);

    float a[8];
#pragma unroll
    for (int j = 0; j < 8; j++) a[j] = 0.f;
    if (o == 0) {   // self
        float4 raw = Yb[(size_t)node * 4 + q];
        acc8(a, raw, 1.f);
    }

    const u16* rowp = ell + node * ELL_CAP;
    int last = min(deg, ELL_CAP) - 1;
    for (int kb = 0; kb <= last; kb += 8) {
        int k0 = kb + o, k1 = kb + 2 + o, k2 = kb + 4 + o, k3 = kb + 6 + o;
        int e0 = min(k0, last), e1 = min(k1, last), e2 = min(k2, last), e3 = min(k3, last);
        int i0 = rowp[e0], i1 = rowp[e1], i2 = rowp[e2], i3 = rowp[e3];
        float4 r0 = Yb[(size_t)i0 * 4 + q];
        float4 r1 = Yb[(size_t)i1 * 4 + q];
        float4 r2 = Yb[(size_t)i2 * 4 + q];
        float4 r3 = Yb[(size_t)i3 * 4 + q];
        float m0 = (k0 <= last) ? 1.f : 0.f;
        float m1 = (k1 <= last) ? 1.f : 0.f;
        float m2 = (k2 <= last) ? 1.f : 0.f;
        float m3 = (k3 <= last) ? 1.f : 0.f;
        acc8(a, r0, m0);
        acc8(a, r1, m1);
        acc8(a, r2, m2);
        acc8(a, r3, m3);
    }

    // reduce over edge-parity (xor 4)
#pragma unroll
    for (int j = 0; j < 8; j++) a[j] += __shfl_xor(a[j], 4, 64);

    float di = rsqrtf((float)(deg + 1));
    int c0 = q * 8;
    float p = 0.f;
#pragma unroll
    for (int j = 0; j < 8; j++)
        p += fmaxf(di * a[j] + b2[c0 + j], 0.0f) * W3[c0 + j];
    p += __shfl_xor(p, 1, 64);
    p += __shfl_xor(p, 2, 64);
    if ((lt & 7) == 0)
        __builtin_nontemporal_store(di * p, &y3t[node * 4 + batch]);
}

// layer-3 aggregation + sigmoid; natural node order (coalesced out writes)
__global__ __launch_bounds__(256) void k_agg3(
        const int* __restrict__ degc, const float4* __restrict__ y3t,
        const u16* __restrict__ ell, const float* __restrict__ b3,
        float* __restrict__ out) {
    int lt = threadIdx.x;
    int node = blockIdx.x * 32 + (lt >> 3);
    if (node >= N_NODES) return;
    int l8 = lt & 7;

    int deg = degc[node];
    const u16* rowp = ell + node * ELL_CAP;
    int last = min(deg, ELL_CAP) - 1;
    float4 a = make_float4(0.f, 0.f, 0.f, 0.f);
    if (l8 == 0) a = y3t[node];       // self
    for (int k = l8; k <= last; k += 16) {
        int e1 = min(k + 8, last);
        int i0 = rowp[k], i1 = rowp[e1];
        float4 g0 = y3t[i0], g1 = y3t[i1];
        float m1 = (k + 8 <= last) ? 1.f : 0.f;
        a.x += g0.x + m1 * g1.x;
        a.y += g0.y + m1 * g1.y;
        a.z += g0.z + m1 * g1.z;
        a.w += g0.w + m1 * g1.w;
    }
#pragma unroll
    for (int m = 1; m <= 4; m <<= 1) {
        a.x += __shfl_xor(a.x, m, 64);
        a.y += __shfl_xor(a.y, m, 64);
        a.z += __shfl_xor(a.z, m, 64);
        a.w += __shfl_xor(a.w, m, 64);
    }
    if (l8 == 0) {
        float di = rsqrtf((float)(deg + 1));
        float bb = b3[0];
        out[0 * N_NODES + node] = 1.0f / (1.0f + expf(-(di * a.x + bb)));
        out[1 * N_NODES + node] = 1.0f / (1.0f + expf(-(di * a.y + bb)));
        out[2 * N_NODES + node] = 1.0f / (1.0f + expf(-(di * a.z + bb)));
        out[3 * N_NODES + node] = 1.0f / (1.0f + expf(-(di * a.w + bb)));
    }
}

// ---------------- launch ----------------

extern "C" void kernel_launch(void* const* d_in, const int* in_sizes, int n_in,
                              void* d_out, int out_size, void* d_ws, size_t ws_size,
                              hipStream_t stream) {
    const float* x   = (const float*)d_in[0];
    const int*   ei  = (const int*)d_in[1];
    const float* W1  = (const float*)d_in[2];
    const float* b1  = (const float*)d_in[3];
    const float* W2  = (const float*)d_in[4];
    const float* b2  = (const float*)d_in[5];
    const float* W3  = (const float*)d_in[6];
    const float* b3  = (const float*)d_in[7];
    float* out = (float*)d_out;

    char* ws = (char*)d_ws;
    size_t off = 0;
    auto carve = [&](size_t bytes) {
        void* p = ws + off;
        off = (off + bytes + 255) & ~(size_t)255;
        return p;
    };
    int*    cnt16  = (int*)   carve((size_t)N_NODES * 16 * 4);
    u16*    ell    = (u16*)   carve((size_t)N_NODES * ELL_CAP * 2);
    int*    degc   = (int*)   carve(N_NODES * 4);
    float4* xd4    = (float4*)carve((size_t)N_NODES * 16);
    __half* y2h    = (__half*)carve((size_t)BN * 32 * 2);
    float*  y3t    = (float*) carve((size_t)N_NODES * 16);
    int*    hist   = (int*)   carve(128 * 4);
    int*    cursor = (int*)   carve(128 * 4);
    int*    perm32 = (int*)   carve(N_NODES * 4);

    dim3 blk(256);

    k_zero    <<<NBLK_N, blk, 0, stream>>>(cnt16, hist);
    k_fill    <<<8 * ((N_EDGES + 255) / 256), blk, 0, stream>>>(ei, cnt16, ell);
    k_prep    <<<NBLK_N, blk, 0, stream>>>(cnt16, x, degc, xd4, hist);
    k_base    <<<1, 128, 0, stream>>>(hist, cursor);
    k_scatter <<<NBLK_N, blk, 0, stream>>>(degc, cursor, perm32);
    k_agg1mv  <<<NBLK_Q, blk, 0, stream>>>(xd4, perm32, ell, W1, b1, W2, y2h);
    k_agg2    <<<8 * NBLK_H8, blk, 0, stream>>>(y2h, perm32, ell, b2, W3, y3t);
    k_agg3    <<<NBLK_N8, blk, 0, stream>>>(degc, (const float4*)y3t, ell, b3, out);
}

// Round 13
// 174.513 us; speedup vs baseline: 1.7802x; 1.7802x over previous
//
#include <hip/hip_runtime.h>
#include <hip/hip_fp16.h>
#include <math.h>

#define N_NODES 50000
#define N_EDGES 800000
#define BATCH   4
#define C1      64
#define C2      32
#define BN      (BATCH * N_NODES)
#define ELL_CAP 64
#define NHALF   (N_NODES / 2)
#define NBLK_N  ((N_NODES + 255) / 256)
#define NBLK_Q  ((N_NODES + 63) / 64)    // 4 lanes/node
#define NBLK_H8 ((NHALF + 31) / 32)      // 8 lanes/unit, half the nodes
#define NBLK_N8 ((N_NODES + 31) / 32)    // 8 lanes/node

typedef unsigned short u16;

// ---------------- build ----------------

// zero the (padded-to-64B) per-node edge counters
__global__ void k_zero(int* __restrict__ cnt16) {
    int n = blockIdx.x * 256 + threadIdx.x;
    if (n < N_NODES) cnt16[n * 16] = 0;
}

// bucketed single-pass ELL fill: block bid handles edges with (dst&7)==(bid&7).
// cnt16 padded to one line/node; ell rows 128B (u16) -> single-writer-XCD lines.
__global__ void k_fill(const int* __restrict__ ei, int* __restrict__ cnt16,
                       u16* __restrict__ ell) {
    int bid = blockIdx.x;
    int r = bid & 7;
    int e = (bid >> 3) * 256 + threadIdx.x;
    if (e >= N_EDGES) return;
    int d = ei[N_EDGES + e];
    if ((d & 7) != r) return;
    int s = ei[e];
    int pos = atomicAdd(&cnt16[d * 16], 1);
    if (pos < ELL_CAP) ell[d * ELL_CAP + pos] = (u16)s;
}

// per node: compact degree, dinv, xd4 = x * dinv (batch-transposed)
__global__ void k_prep(const int* __restrict__ cnt16, const float* __restrict__ x,
                       int* __restrict__ degc, float* __restrict__ dinv,
                       float4* __restrict__ xd4) {
    int n = blockIdx.x * 256 + threadIdx.x;
    if (n >= N_NODES) return;
    int deg = cnt16[n * 16];
    degc[n] = deg;
    float di = rsqrtf((float)(deg + 1));   // +1 self-loop
    dinv[n] = di;
    float4 w;
    w.x = x[n] * di;
    w.y = x[N_NODES + n] * di;
    w.z = x[2 * N_NODES + n] * di;
    w.w = x[3 * N_NODES + n] * di;
    xd4[n] = w;
}

// ---------------- compute ----------------

// fused: layer-1 aggregation (4 lanes/node, batch-shared float4 gathers) +
// dense matvec per lane (lane q = batch q): h1=relu(px*W1+b1); y2=dinv*(h1@W2) fp16
__global__ __launch_bounds__(256) void k_agg1mv(
        const float* __restrict__ dinv, const float4* __restrict__ xd4,
        const int* __restrict__ degc, const u16* __restrict__ ell,
        const float* __restrict__ W1, const float* __restrict__ b1,
        const float* __restrict__ W2, __half* __restrict__ y2h) {
    __shared__ float sW1[C1], sb1[C1], sW2[C1 * C2];
    int lt = threadIdx.x;
    for (int i = lt; i < C1; i += 256) { sW1[i] = W1[i]; sb1[i] = b1[i]; }
    for (int i = lt; i < C1 * C2; i += 256) sW2[i] = W2[i];
    __syncthreads();

    int node = blockIdx.x * 64 + (lt >> 2);
    if (node >= N_NODES) return;
    int q = lt & 3;

    int deg = degc[node];
    const u16* rowp = ell + node * ELL_CAP;
    int last = deg - 1;
    float4 a = make_float4(0.f, 0.f, 0.f, 0.f);
    if (q == 0) a = xd4[node];        // self
    for (int k = q; k <= last; k += 16) {
        int e1 = min(k + 4, last), e2 = min(k + 8, last), e3 = min(k + 12, last);
        int i0 = rowp[k], i1 = rowp[e1], i2 = rowp[e2], i3 = rowp[e3];
        float4 g0 = xd4[i0], g1 = xd4[i1], g2 = xd4[i2], g3 = xd4[i3];
        float m1 = (k + 4 <= last) ? 1.f : 0.f;
        float m2 = (k + 8 <= last) ? 1.f : 0.f;
        float m3 = (k + 12 <= last) ? 1.f : 0.f;
        a.x += (g0.x + m1 * g1.x) + (m2 * g2.x + m3 * g3.x);
        a.y += (g0.y + m1 * g1.y) + (m2 * g2.y + m3 * g3.y);
        a.z += (g0.z + m1 * g1.z) + (m2 * g2.z + m3 * g3.z);
        a.w += (g0.w + m1 * g1.w) + (m2 * g2.w + m3 * g3.w);
    }
#pragma unroll
    for (int m = 1; m <= 2; m <<= 1) {
        a.x += __shfl_xor(a.x, m, 64);
        a.y += __shfl_xor(a.y, m, 64);
        a.z += __shfl_xor(a.z, m, 64);
        a.w += __shfl_xor(a.w, m, 64);
    }

    float di = dinv[node];
    float px = (q == 0) ? a.x : (q == 1) ? a.y : (q == 2) ? a.z : a.w;
    px *= di;                          // lane q <- propagated input for batch q

    float acc[C2];
#pragma unroll
    for (int j = 0; j < C2; j++) acc[j] = 0.0f;
    for (int c = 0; c < C1; c++) {
        float h = fmaxf(px * sW1[c] + sb1[c], 0.0f);
        const float4* rw = (const float4*)&sW2[c * C2];
#pragma unroll
        for (int j4 = 0; j4 < C2 / 4; j4++) {
            float4 w = rw[j4];
            acc[4 * j4 + 0] += h * w.x;
            acc[4 * j4 + 1] += h * w.y;
            acc[4 * j4 + 2] += h * w.z;
            acc[4 * j4 + 3] += h * w.w;
        }
    }

    __half2 hbuf[16];
#pragma unroll
    for (int j = 0; j < 16; j++)
        hbuf[j] = __floats2half2_rn(acc[2 * j] * di, acc[2 * j + 1] * di);
    float4* dst = (float4*)(y2h + ((size_t)q * N_NODES + node) * 32);
    const float4* srcb = (const float4*)hbuf;
#pragma unroll
    for (int j4 = 0; j4 < 4; j4++) dst[j4] = srcb[j4];
}

// add 8 fp16 channels (one 16B chunk) into fp32 accumulator with mask
__device__ __forceinline__ void acc8(float* a, float4 raw, float m) {
    const __half2* hp = (const __half2*)&raw;
#pragma unroll
    for (int j = 0; j < 4; j++) {
        float2 f = __half22float2(hp[j]);
        a[2 * j + 0] += m * f.x;
        a[2 * j + 1] += m * f.y;
    }
}

// layer-2 aggregation (fp16 64B rows, 1 line/edge/batch) + epilogue + layer-3 dot.
// XCD-affine: xcd=blk&7 -> batch=xcd>>1, nodehalf=xcd&1 (slice ~4.8MB ~ L2-fit).
// 8 lanes/unit: o=edge parity, q=channel chunk. Unique writer -> plain store.
__global__ __launch_bounds__(256) void k_agg2(
        const __half* __restrict__ y2h, const int* __restrict__ degc,
        const u16* __restrict__ ell, const float* __restrict__ dinv,
        const float* __restrict__ b2, const float* __restrict__ W3,
        float* __restrict__ y3t) {
    int blk = blockIdx.x;
    int xcd = blk & 7;
    int batch = xcd >> 1;
    int nh = xcd & 1;
    int sub = blk >> 3;
    int lt = threadIdx.x;
    int unit = sub * 32 + (lt >> 3);
    if (unit >= NHALF) return;
    int node = nh * NHALF + unit;
    int o = (lt >> 2) & 1;
    int q = lt & 3;

    const float4* Yb = (const float4*)(y2h + (size_t)batch * N_NODES * 32);

    float a[8];
#pragma unroll
    for (int j = 0; j < 8; j++) a[j] = 0.f;
    if (o == 0) {   // self
        float4 raw = Yb[(size_t)node * 4 + q];
        acc8(a, raw, 1.f);
    }

    int deg = degc[node];
    const u16* rowp = ell + node * ELL_CAP;
    int last = deg - 1;
    for (int kb = 0; kb <= last; kb += 8) {
        int k0 = kb + o, k1 = kb + 2 + o, k2 = kb + 4 + o, k3 = kb + 6 + o;
        int e0 = min(k0, last), e1 = min(k1, last), e2 = min(k2, last), e3 = min(k3, last);
        int i0 = rowp[e0], i1 = rowp[e1], i2 = rowp[e2], i3 = rowp[e3];
        float4 r0 = Yb[(size_t)i0 * 4 + q];
        float4 r1 = Yb[(size_t)i1 * 4 + q];
        float4 r2 = Yb[(size_t)i2 * 4 + q];
        float4 r3 = Yb[(size_t)i3 * 4 + q];
        float m0 = (k0 <= last) ? 1.f : 0.f;
        float m1 = (k1 <= last) ? 1.f : 0.f;
        float m2 = (k2 <= last) ? 1.f : 0.f;
        float m3 = (k3 <= last) ? 1.f : 0.f;
        acc8(a, r0, m0);
        acc8(a, r1, m1);
        acc8(a, r2, m2);
        acc8(a, r3, m3);
    }

    // reduce over edge-parity (xor 4)
#pragma unroll
    for (int j = 0; j < 8; j++) a[j] += __shfl_xor(a[j], 4, 64);

    float di = dinv[node];
    int c0 = q * 8;
    float p = 0.f;
#pragma unroll
    for (int j = 0; j < 8; j++)
        p += fmaxf(di * a[j] + b2[c0 + j], 0.0f) * W3[c0 + j];
    p += __shfl_xor(p, 1, 64);
    p += __shfl_xor(p, 2, 64);
    if ((lt & 7) == 0) y3t[node * 4 + batch] = di * p;   // unique writer
}

// layer-3 aggregation + sigmoid; 8 lanes/node, unroll-2 (16 edges in flight)
__global__ __launch_bounds__(256) void k_agg3(
        const float* __restrict__ dinv, const float4* __restrict__ y3t,
        const int* __restrict__ degc, const u16* __restrict__ ell,
        const float* __restrict__ b3, float* __restrict__ out) {
    int lt = threadIdx.x;
    int node = blockIdx.x * 32 + (lt >> 3);
    if (node >= N_NODES) return;
    int l8 = lt & 7;

    int deg = degc[node];
    const u16* rowp = ell + node * ELL_CAP;
    int last = deg - 1;
    float4 a = make_float4(0.f, 0.f, 0.f, 0.f);
    if (l8 == 0) a = y3t[node];       // self
    for (int k = l8; k <= last; k += 16) {
        int e1 = min(k + 8, last);
        int i0 = rowp[k], i1 = rowp[e1];
        float4 g0 = y3t[i0], g1 = y3t[i1];
        float m1 = (k + 8 <= last) ? 1.f : 0.f;
        a.x += g0.x + m1 * g1.x;
        a.y += g0.y + m1 * g1.y;
        a.z += g0.z + m1 * g1.z;
        a.w += g0.w + m1 * g1.w;
    }
#pragma unroll
    for (int m = 1; m <= 4; m <<= 1) {
        a.x += __shfl_xor(a.x, m, 64);
        a.y += __shfl_xor(a.y, m, 64);
        a.z += __shfl_xor(a.z, m, 64);
        a.w += __shfl_xor(a.w, m, 64);
    }
    if (l8 == 0) {
        float di = dinv[node];
        float bb = b3[0];
        out[0 * N_NODES + node] = 1.0f / (1.0f + expf(-(di * a.x + bb)));
        out[1 * N_NODES + node] = 1.0f / (1.0f + expf(-(di * a.y + bb)));
        out[2 * N_NODES + node] = 1.0f / (1.0f + expf(-(di * a.z + bb)));
        out[3 * N_NODES + node] = 1.0f / (1.0f + expf(-(di * a.w + bb)));
    }
}

// ---------------- launch ----------------

extern "C" void kernel_launch(void* const* d_in, const int* in_sizes, int n_in,
                              void* d_out, int out_size, void* d_ws, size_t ws_size,
                              hipStream_t stream) {
    const float* x   = (const float*)d_in[0];
    const int*   ei  = (const int*)d_in[1];
    const float* W1  = (const float*)d_in[2];
    const float* b1  = (const float*)d_in[3];
    const float* W2  = (const float*)d_in[4];
    const float* b2  = (const float*)d_in[5];
    const float* W3  = (const float*)d_in[6];
    const float* b3  = (const float*)d_in[7];
    float* out = (float*)d_out;

    char* ws = (char*)d_ws;
    size_t off = 0;
    auto carve = [&](size_t bytes) {
        void* p = ws + off;
        off = (off + bytes + 255) & ~(size_t)255;
        return p;
    };
    int*    cnt16 = (int*)   carve((size_t)N_NODES * 16 * 4);
    u16*    ell   = (u16*)   carve((size_t)N_NODES * ELL_CAP * 2);
    int*    degc  = (int*)   carve(N_NODES * 4);
    float*  dinv  = (float*) carve(N_NODES * 4);
    float4* xd4   = (float4*)carve((size_t)N_NODES * 16);
    __half* y2h   = (__half*)carve((size_t)BN * 32 * 2);
    float*  y3t   = (float*) carve((size_t)N_NODES * 16);

    dim3 blk(256);

    k_zero   <<<NBLK_N, blk, 0, stream>>>(cnt16);
    k_fill   <<<8 * ((N_EDGES + 255) / 256), blk, 0, stream>>>(ei, cnt16, ell);
    k_prep   <<<NBLK_N, blk, 0, stream>>>(cnt16, x, degc, dinv, xd4);
    k_agg1mv <<<NBLK_Q, blk, 0, stream>>>(dinv, xd4, degc, ell, W1, b1, W2, y2h);
    k_agg2   <<<8 * NBLK_H8, blk, 0, stream>>>(y2h, degc, ell, dinv, b2, W3, y3t);
    k_agg3   <<<NBLK_N8, blk, 0, stream>>>(dinv, (const float4*)y3t, degc, ell, b3, out);
}